// Round 5
// baseline (148.178 us; speedup 1.0000x reference)
//
#include <hip/hip_runtime.h>

#define LN_EPS 1e-5f
#define D 768
#define D4 192          // D/4
#define TWO_D 1536

typedef float f4 __attribute__((ext_vector_type(4)));

// ws layout (floats): P0[1536] = gamma*w0, P1[1536] = gamma*w1,
//                     consts[4] = {C0, C1, E0+gb0, E1+gb1}
// Logits: l_k = rstd*(A_k - mean*C_k) + E_k + gb_k, A_k = sum h*gamma*w_k.

__global__ __launch_bounds__(64) void setup_kernel(
    const float* __restrict__ gamma, const float* __restrict__ beta,
    const float* __restrict__ gate_w, const float* __restrict__ gate_b,
    float* __restrict__ ws)
{
    const int lane = threadIdx.x;           // single wave
    const f4* g4  = (const f4*)gamma;
    const f4* b4  = (const f4*)beta;
    const f4* w04 = (const f4*)gate_w;
    const f4* w14 = (const f4*)(gate_w + TWO_D);
    f4* P04 = (f4*)ws;
    f4* P14 = (f4*)(ws + TWO_D);

    float C0 = 0.f, C1 = 0.f, E0 = 0.f, E1 = 0.f;
    #pragma unroll
    for (int j = 0; j < 6; ++j) {
        const int idx = j * 64 + lane;
        f4 g = g4[idx], bb = b4[idx], w0 = w04[idx], w1 = w14[idx];
        f4 p0 = g * w0;
        f4 p1 = g * w1;
        P04[idx] = p0;
        P14[idx] = p1;
        C0 += p0.x + p0.y + p0.z + p0.w;
        C1 += p1.x + p1.y + p1.z + p1.w;
        E0 += bb.x * w0.x + bb.y * w0.y + bb.z * w0.z + bb.w * w0.w;
        E1 += bb.x * w1.x + bb.y * w1.y + bb.z * w1.z + bb.w * w1.w;
    }
    #pragma unroll
    for (int off = 32; off > 0; off >>= 1) {
        C0 += __shfl_xor(C0, off, 64);
        C1 += __shfl_xor(C1, off, 64);
        E0 += __shfl_xor(E0, off, 64);
        E1 += __shfl_xor(E1, off, 64);
    }
    if (lane == 0) {
        float* c = ws + 2 * TWO_D;
        c[0] = C0;
        c[1] = C1;
        c[2] = E0 + gate_b[0];
        c[3] = E1 + gate_b[1];
    }
}

// Persistent waves, grid-stride by wave id, software-pipelined: row k+1's
// 6 HBM loads are in flight while row k is reduced/blended/stored.
// P0/P1/consts live in LDS (12 KB/block) -> param reads never contend with
// the streaming data path or get evicted from L1 by it.
__global__ __launch_bounds__(256) void fused_gate_kernel(
    const float* __restrict__ seq, const float* __restrict__ msa,
    const float* __restrict__ ws, float* __restrict__ out,
    int nrows, int nwaves)
{
    __shared__ float ldsbuf[2 * TWO_D + 4];

    // ---- one-time cooperative stage of params into LDS ----
    {
        const f4* w4 = (const f4*)ws;
        f4* l4 = (f4*)ldsbuf;
        #pragma unroll
        for (int t = 0; t < 3; ++t)
            l4[threadIdx.x + t * 256] = w4[threadIdx.x + t * 256];   // 768 f4 total
        if (threadIdx.x < 4)
            ldsbuf[2 * TWO_D + threadIdx.x] = ws[2 * TWO_D + threadIdx.x];
    }
    __syncthreads();

    const int wave = threadIdx.x >> 6;
    const int lane = threadIdx.x & 63;
    int r = blockIdx.x * 4 + wave;
    if (r >= nrows) return;

    const f4* P0l = (const f4*)ldsbuf;
    const f4* P1l = (const f4*)(ldsbuf + TWO_D);
    const float C0c = ldsbuf[2 * TWO_D + 0];
    const float C1c = ldsbuf[2 * TWO_D + 1];
    const float E0c = ldsbuf[2 * TWO_D + 2];
    const float E1c = ldsbuf[2 * TWO_D + 3];
    const float inv_n = 1.f / (float)TWO_D;

    // ---- prologue: load first row ----
    f4 s[3], m[3];
    {
        const f4* sp = (const f4*)(seq + (size_t)r * D);
        const f4* mp = (const f4*)(msa + (size_t)r * D);
        #pragma unroll
        for (int j = 0; j < 3; ++j) {
            s[j] = __builtin_nontemporal_load(&sp[j * 64 + lane]);
            m[j] = __builtin_nontemporal_load(&mp[j * 64 + lane]);
        }
    }

    for (;;) {
        const int rn = r + nwaves;
        const bool more = rn < nrows;

        // ---- prefetch next row (stays in flight through the compute below) ----
        f4 ns[3], nm[3];
        if (more) {
            const f4* snp = (const f4*)(seq + (size_t)rn * D);
            const f4* mnp = (const f4*)(msa + (size_t)rn * D);
            #pragma unroll
            for (int j = 0; j < 3; ++j) {
                ns[j] = __builtin_nontemporal_load(&snp[j * 64 + lane]);
                nm[j] = __builtin_nontemporal_load(&mnp[j * 64 + lane]);
            }
        }

        // ---- fused pass: su, sq, a0, a1 (params from LDS) ----
        float su = 0.f, sq = 0.f, a0 = 0.f, a1 = 0.f;
        #pragma unroll
        for (int j = 0; j < 6; ++j) {
            const int idx = (j < 3) ? (j * 64 + lane) : (D4 + (j - 3) * 64 + lane);
            const f4 p0 = P0l[idx];
            const f4 p1 = P1l[idx];
            const f4 h = (j < 3) ? s[j] : m[j - 3];
            su += h.x + h.y + h.z + h.w;
            sq += h.x * h.x + h.y * h.y + h.z * h.z + h.w * h.w;
            a0 += h.x * p0.x + h.y * p0.y + h.z * p0.z + h.w * p0.w;
            a1 += h.x * p1.x + h.y * p1.y + h.z * p1.z + h.w * p1.w;
        }
        #pragma unroll
        for (int off = 32; off > 0; off >>= 1) {
            su += __shfl_xor(su, off, 64);
            sq += __shfl_xor(sq, off, 64);
            a0 += __shfl_xor(a0, off, 64);
            a1 += __shfl_xor(a1, off, 64);
        }

        // ---- epilogue + store ----
        const float mean = su * inv_n;
        const float var  = fmaxf(sq * inv_n - mean * mean, 0.f);
        const float rstd = rsqrtf(var + LN_EPS);
        const float l0 = rstd * (a0 - mean * C0c) + E0c;
        const float l1 = rstd * (a1 - mean * C1c) + E1c;
        const float mx = fmaxf(l0, l1);
        const float e0 = __expf(l0 - mx), e1 = __expf(l1 - mx);
        const float inv = 1.f / (e0 + e1);
        const float w0s = e0 * inv, w1s = e1 * inv;

        f4* o4 = (f4*)(out + (size_t)r * D);
        #pragma unroll
        for (int j = 0; j < 3; ++j) {
            f4 o = w0s * s[j] + w1s * m[j];
            __builtin_nontemporal_store(o, &o4[j * 64 + lane]);
        }

        if (!more) break;
        #pragma unroll
        for (int j = 0; j < 3; ++j) { s[j] = ns[j]; m[j] = nm[j]; }
        r = rn;
    }
}

extern "C" void kernel_launch(void* const* d_in, const int* in_sizes, int n_in,
                              void* d_out, int out_size, void* d_ws, size_t ws_size,
                              hipStream_t stream) {
    const float* seq    = (const float*)d_in[0];
    const float* msa    = (const float*)d_in[1];
    const float* gamma  = (const float*)d_in[2];
    const float* beta   = (const float*)d_in[3];
    const float* gate_w = (const float*)d_in[4];
    const float* gate_b = (const float*)d_in[5];
    float* out = (float*)d_out;
    float* ws  = (float*)d_ws;

    const int nrows = in_sizes[0] / D;              // 16384
    setup_kernel<<<1, 64, 0, stream>>>(gamma, beta, gate_w, gate_b, ws);
    const int blocks = 1024;                        // persistent: 4 rows per wave
    const int nwaves = blocks * 4;
    fused_gate_kernel<<<blocks, 256, 0, stream>>>(seq, msa, ws, out, nrows, nwaves);
}

// Round 6
// 147.583 us; speedup vs baseline: 1.0040x; 1.0040x over previous
//
#include <hip/hip_runtime.h>

#define LN_EPS 1e-5f
#define D 768
#define D4 192          // D/4
#define TWO_D 1536
#define RPW 4           // rows per wave

typedef float f4 __attribute__((ext_vector_type(4)));

// Single kernel, no setup dispatch. Logits via the algebraic refactor:
//   l_k = rstd*(A_k - mean*C_k) + E_k + gb_k
//   A_k = sum_i h_i*gamma_i*w_k_i  (per-row, reduced)
//   C_k = sum_i gamma_i*w_k_i      (row-independent, computed per wave from
//   E_k = sum_i beta_i *w_k_i       L1-resident params, amortized over 4 rows)
// Each wave: 4 rows, all 24 HBM float4 loads issued before any arithmetic,
// one 20-chain butterfly, 4 epilogues with nontemporal stores.
__global__ __launch_bounds__(256) void fused_gate_kernel(
    const float* __restrict__ seq, const float* __restrict__ msa,
    const float* __restrict__ gamma, const float* __restrict__ beta,
    const float* __restrict__ gate_w, const float* __restrict__ gate_b,
    float* __restrict__ out, int nrows)
{
    const int wave = threadIdx.x >> 6;
    const int lane = threadIdx.x & 63;
    const int base = (blockIdx.x * 4 + wave) * RPW;
    if (base >= nrows) return;

    int rr[RPW];
    bool valid[RPW];
    #pragma unroll
    for (int i = 0; i < RPW; ++i) {
        const int r = base + i;
        valid[i] = (r < nrows);
        rr[i] = valid[i] ? r : (nrows - 1);
    }

    // ---- issue ALL data loads before any arithmetic (max MLP) ----
    f4 s[RPW][3], m[RPW][3];
    #pragma unroll
    for (int i = 0; i < RPW; ++i) {
        const f4* sp = (const f4*)(seq + (size_t)rr[i] * D);
        const f4* mp = (const f4*)(msa + (size_t)rr[i] * D);
        #pragma unroll
        for (int j = 0; j < 3; ++j) {
            s[i][j] = __builtin_nontemporal_load(&sp[j * 64 + lane]);
            m[i][j] = __builtin_nontemporal_load(&mp[j * 64 + lane]);
        }
    }

    const f4* g4  = (const f4*)gamma;
    const f4* b4  = (const f4*)beta;
    const f4* w04 = (const f4*)gate_w;
    const f4* w14 = (const f4*)(gate_w + TWO_D);

    // ---- fused pass: params on the fly (L1-resident), 4 rows share them ----
    float C0 = 0.f, C1 = 0.f, E0 = 0.f, E1 = 0.f;
    float su[RPW], sq[RPW], a0[RPW], a1[RPW];
    #pragma unroll
    for (int i = 0; i < RPW; ++i) { su[i] = sq[i] = a0[i] = a1[i] = 0.f; }

    #pragma unroll
    for (int j = 0; j < 6; ++j) {
        const int idx = (j < 3) ? (j * 64 + lane) : (D4 + (j - 3) * 64 + lane);
        const f4 g = g4[idx], bb = b4[idx], w0 = w04[idx], w1 = w14[idx];
        const f4 p0 = g * w0;
        const f4 p1 = g * w1;
        C0 += p0.x + p0.y + p0.z + p0.w;
        C1 += p1.x + p1.y + p1.z + p1.w;
        E0 += bb.x * w0.x + bb.y * w0.y + bb.z * w0.z + bb.w * w0.w;
        E1 += bb.x * w1.x + bb.y * w1.y + bb.z * w1.z + bb.w * w1.w;
        #pragma unroll
        for (int i = 0; i < RPW; ++i) {
            const f4 h = (j < 3) ? s[i][j] : m[i][j - 3];
            su[i] += h.x + h.y + h.z + h.w;
            sq[i] += h.x * h.x + h.y * h.y + h.z * h.z + h.w * h.w;
            a0[i] += h.x * p0.x + h.y * p0.y + h.z * p0.z + h.w * p0.w;
            a1[i] += h.x * p1.x + h.y * p1.y + h.z * p1.z + h.w * p1.w;
        }
    }

    // ---- one butterfly round, 20 independent chains ----
    #pragma unroll
    for (int off = 32; off > 0; off >>= 1) {
        C0 += __shfl_xor(C0, off, 64);
        C1 += __shfl_xor(C1, off, 64);
        E0 += __shfl_xor(E0, off, 64);
        E1 += __shfl_xor(E1, off, 64);
        #pragma unroll
        for (int i = 0; i < RPW; ++i) {
            su[i] += __shfl_xor(su[i], off, 64);
            sq[i] += __shfl_xor(sq[i], off, 64);
            a0[i] += __shfl_xor(a0[i], off, 64);
            a1[i] += __shfl_xor(a1[i], off, 64);
        }
    }

    const float gb0 = gate_b[0], gb1 = gate_b[1];
    const float inv_n = 1.f / (float)TWO_D;

    // ---- epilogues + stores ----
    #pragma unroll
    for (int i = 0; i < RPW; ++i) {
        if (!valid[i]) continue;
        const float mean = su[i] * inv_n;
        const float var  = fmaxf(sq[i] * inv_n - mean * mean, 0.f);
        const float rstd = rsqrtf(var + LN_EPS);
        const float l0 = rstd * (a0[i] - mean * C0) + E0 + gb0;
        const float l1 = rstd * (a1[i] - mean * C1) + E1 + gb1;
        const float mx = fmaxf(l0, l1);
        const float e0 = __expf(l0 - mx), e1 = __expf(l1 - mx);
        const float inv = 1.f / (e0 + e1);
        const float w0s = e0 * inv, w1s = e1 * inv;
        f4* o4 = (f4*)(out + (size_t)rr[i] * D);
        #pragma unroll
        for (int j = 0; j < 3; ++j) {
            f4 o = w0s * s[i][j] + w1s * m[i][j];
            __builtin_nontemporal_store(o, &o4[j * 64 + lane]);
        }
    }
}

extern "C" void kernel_launch(void* const* d_in, const int* in_sizes, int n_in,
                              void* d_out, int out_size, void* d_ws, size_t ws_size,
                              hipStream_t stream) {
    const float* seq    = (const float*)d_in[0];
    const float* msa    = (const float*)d_in[1];
    const float* gamma  = (const float*)d_in[2];
    const float* beta   = (const float*)d_in[3];
    const float* gate_w = (const float*)d_in[4];
    const float* gate_b = (const float*)d_in[5];
    float* out = (float*)d_out;

    const int nrows = in_sizes[0] / D;                  // 16384
    const int rows_per_block = 4 * RPW;                 // 16
    const int blocks = (nrows + rows_per_block - 1) / rows_per_block;  // 1024
    fused_gate_kernel<<<blocks, 256, 0, stream>>>(
        seq, msa, gamma, beta, gate_w, gate_b, out, nrows);
}